// Round 2
// baseline (670.279 us; speedup 1.0000x reference)
//
#include <hip/hip_runtime.h>
#include <stdint.h>

// LocallyConnected2D: out[b,f,or,oc] = relu( sum_{c,kh,kw} x[b,c,2or+kh,2oc+kw]*W[f,c,2or+kh,2oc+kw] + bias )
// bias raw-reshape: bias_flat[f*OR*OC + or*OC + oc]
//
// B=32 C=32 H=128 W=128 F=64 OR=OC=64. ~236 MB ideal -> ~37 us HBM floor.
// R6 vs R5 (108 us/dispatch): R5's VGPR_Count=52 proved the compiler SANK all frag loads
// to just-before-use (ping-pong live set 96+ can't fit in 52) -> every s-iter exposed full
// W-load latency, and all 16 waves stalled together in one barrier domain.
//  - asm volatile memory fences between load-issue(s+1) and FMA(s): loads must be EMITTED
//    early (fence orders memory ops), waitcnts stay at first use -> true 2-deep pipeline.
//    Verify: VGPR_Count ~115-128 (52 = fence failed; 128+scratch = spilled).
//  - f-split: 512 blocks x 512 thr (8 waves, 32 f). 2 blocks/CU (LDS 64KB ea) = two
//    independent barrier domains; same 16 waves/CU. Pair (id, id+256) shares the x tile
//    and the XCD (256%8==0) so the duplicated x read hits L2/L3.

#define CC  32
#define HH  128
#define WWD 128
#define FF  64
#define ORR 64
#define OCC 64
#define CB  4            // channels per chunk
#define NIT (CC / CB)    // 8
#define CSTRIDE (CB * HH * WWD)   // 65536 floats per chunk advance
#define CHW (CC * HH * WWD)       // 524288 floats per f plane

#define XBUF 8192        // CB*2kh*32b*32w floats = 32 KB per buffer

__global__ __launch_bounds__(512, 4) void lc2d_kernel(
    const float* __restrict__ x, const float* __restrict__ wgt,
    const float* __restrict__ bias, float* __restrict__ out)
{
    __shared__ __align__(16) float Xs[2][XBUF];   // 64 KB total -> 2 blocks/CU

    const int tid  = threadIdx.x;
    const int id   = blockIdx.x;          // [0,512)
    const int fblk = id >> 8;             // 0..1 : which 32-f half
    const int low  = id & 255;
    // oc-pairs sharing 128-B output lines get ids differing by 128 (same id%8 ->
    // same XCD) so L2 merges their half-line writes.
    const int oct = ((low & 1) << 1) | (low >> 7);   // 0..3 -> oc0 = oct*16
    const int orr = (low >> 1) & 63;
    const int w0  = oct * 32;                         // 32 w-floats = 128 B aligned
    const int h0  = orr * 2;

    const int lane = tid & 63;
    const int wv   = tid >> 6;        // wave id 0..7
    const int chk  = lane & 7;        // 16-B chunk within a 128-B global row
    const int sub  = lane >> 3;       // sub-row within a slot of 8 rows

    // ---- x staging. LDS row r in [0,256): r = s*32 + b, s = ci*2+kh.
    // wave wv stages rows j*64 + wv*8 + sub for j=0..3 (4 global_load_lds per issue).
    const float* gx[4];
#pragma unroll
    for (int j = 0; j < 4; ++j) {
        const int r = j * 64 + wv * 8 + sub;
        gx[j] = x + (((((r & 31) * CC) + (r >> 6)) * HH) + h0 + ((r >> 5) & 1)) * WWD + w0 + chk * 4;
    }

    auto issue = [&](int p) {
#pragma unroll
        for (int j = 0; j < 4; ++j) {
            __builtin_amdgcn_global_load_lds(
                (const __attribute__((address_space(1))) void*)gx[j],
                (__attribute__((address_space(3))) void*)(&Xs[p][j * 2048 + wv * 256]), 16, 0, 0);
            gx[j] += CSTRIDE;
        }
    };

    // ---- compute thread mapping: ocg = w 4-chunk (2 oc), bg -> 4 b, wv -> 4 f
    const int ocg = tid & 7;
    const int bg  = (tid >> 3) & 7;
    const int xoff = bg * 128 + ocg * 4;   // (bg*4)*32 + ocg*4

    // W fragment pointers for f = fblk*32 + wv*4 + q. Per (s,q) load: 8 ocg-lanes x 16 B
    // = one 128-B line, duplicated across 8 bg-lanes (coalescer merges same-address lanes).
    const float* wq[4];
#pragma unroll
    for (int q = 0; q < 4; ++q)
        wq[q] = wgt + (size_t)(fblk * 32 + wv * 4 + q) * CHW + (h0 * WWD) + w0 + ocg * 4;

    float acc0[4][4], acc1[4][4];          // [i=b][q=f], oc even / oc odd
#pragma unroll
    for (int i = 0; i < 4; ++i)
#pragma unroll
        for (int q = 0; q < 4; ++q) { acc0[i][q] = 0.f; acc1[i][q] = 0.f; }

    issue(0);
    __syncthreads();                       // chunk 0 staged (implicit vmcnt drain)

    for (int it = 0; it < NIT; ++it) {
        const int p = it & 1;
        if (it + 1 < NIT) issue(p ^ 1);    // overlaps the whole compute phase below

        const float* Xp = Xs[p];
        float4 xa[2][4], wb[2][4];
        // preload s = 0 (ci=0, kh=0)
        {
            const float4* xr = (const float4*)(Xp + xoff);
#pragma unroll
            for (int i = 0; i < 4; ++i) xa[0][i] = xr[i * 8];   // b = bg*4 + i
#pragma unroll
            for (int q = 0; q < 4; ++q) wb[0][q] = *(const float4*)(wq[q]);
        }
        asm volatile("" ::: "memory");     // pin preload issue before the loop body
#pragma unroll
        for (int s = 0; s < 2 * CB; ++s) {       // s = ci*2 + kh, fully unrolled
            const int cur = s & 1, nxt = cur ^ 1;
            if (s + 1 < 2 * CB) {
                const int sn  = s + 1;
                const int off = ((sn >> 1) * HH + (sn & 1)) * WWD;   // compile-time
                const float4* xr = (const float4*)(Xp + sn * 1024 + xoff);
#pragma unroll
                for (int i = 0; i < 4; ++i) xa[nxt][i] = xr[i * 8];
#pragma unroll
                for (int q = 0; q < 4; ++q) wb[nxt][q] = *(const float4*)(wq[q] + off);
            }
            // fence: loads for s+1 must be EMITTED before this point; FMAs (reg-only)
            // schedule freely, waitcnts remain at first use in iter s+1.
            asm volatile("" ::: "memory");
#pragma unroll
            for (int i = 0; i < 4; ++i)
#pragma unroll
                for (int q = 0; q < 4; ++q) {
                    acc0[i][q] = fmaf(xa[cur][i].x, wb[cur][q].x, acc0[i][q]);
                    acc0[i][q] = fmaf(xa[cur][i].y, wb[cur][q].y, acc0[i][q]);
                    acc1[i][q] = fmaf(xa[cur][i].z, wb[cur][q].z, acc1[i][q]);
                    acc1[i][q] = fmaf(xa[cur][i].w, wb[cur][q].w, acc1[i][q]);
                }
        }
#pragma unroll
        for (int q = 0; q < 4; ++q) wq[q] += CSTRIDE;
        // one barrier per chunk: readers of Xs[p] done; staging of chunk it+1 (issued at
        // top, a full compute phase ago) completes within the drain for ~free.
        __syncthreads();
    }

    // ---- epilogue: bias (raw reshape [F][OR][OC]) + relu, float2 per (b,f)
    const int oc0 = oct * 16 + ocg * 2;
#pragma unroll
    for (int q = 0; q < 4; ++q) {
        const int f = fblk * 32 + wv * 4 + q;
        const float2 bv = *(const float2*)(bias + f * (ORR * OCC) + orr * OCC + oc0);
#pragma unroll
        for (int i = 0; i < 4; ++i) {
            const int b = bg * 4 + i;
            float2 o;
            o.x = fmaxf(acc0[i][q] + bv.x, 0.f);
            o.y = fmaxf(acc1[i][q] + bv.y, 0.f);
            *(float2*)(out + (((b * FF + f) * ORR + orr) * OCC) + oc0) = o;
        }
    }
}

extern "C" void kernel_launch(void* const* d_in, const int* in_sizes, int n_in,
                              void* d_out, int out_size, void* d_ws, size_t ws_size,
                              hipStream_t stream) {
    (void)in_sizes; (void)n_in; (void)d_ws; (void)ws_size; (void)out_size;
    const float* x    = (const float*)d_in[0];
    const float* wgt  = (const float*)d_in[1];
    const float* bias = (const float*)d_in[2];
    float* out        = (float*)d_out;
    lc2d_kernel<<<dim3(512, 1, 1), dim3(512, 1, 1), 0, stream>>>(x, wgt, bias, out);
}

// Round 3
// 263.384 us; speedup vs baseline: 2.5449x; 2.5449x over previous
//
#include <hip/hip_runtime.h>
#include <stdint.h>

// LocallyConnected2D: out[b,f,or,oc] = relu( sum_{c,kh,kw} x[b,c,2or+kh,2oc+kw]*W[f,c,2or+kh,2oc+kw] + bias )
// bias raw-reshape: bias_flat[f*OR*OC + or*OC + oc]
//
// B=32 C=32 H=128 W=128 F=64 OR=OC=64. ~236 MB ideal -> ~37 us HBM floor.
//
// R7 vs R6 (514 us, scratch disaster) and R5 (108 us):
//  - R6 post-mortem: "memory" asm fences forced xa/wb to SCRATCH (VGPR 64 + WRITE_SIZE
//    884 MB). Fences removed permanently.
//  - Root bug in R4/R5: __syncthreads() emits s_waitcnt vmcnt(0) before s_barrier ->
//    the staging pipeline fully drained EVERY chunk (burst-then-drain; sustained HBM
//    only 1.3 TB/s). Fix (T3+T4): raw __builtin_amdgcn_s_barrier() + hand-counted
//    s_waitcnt vmcnt(N), never 0 in the main loop.
//  - Both X and W staged via global_load_lds into a 4-deep circular buffer (CB=1:
//    one channel/chunk, X 8KB + W 8KB). Exactly 2 gload_lds per wave per chunk ->
//    steady-state wait vmcnt(6) = 3 chunks in flight; tail peels 4/2/0.
//  - f-split: 512 blocks x 512 thr, 64 KB LDS -> 2 blocks/CU (two barrier domains),
//    16 waves/CU. Pair (id, id+256) shares the x tile on the same XCD (256%8==0).
//  - W LDS reads are wave-broadcast (8 lanes same addr) -> conflict-free.

#define CC  32
#define HH  128
#define WWD 128
#define FF  64
#define ORR 64
#define OCC 64
#define NIT 32                 // chunks = channels (CB=1)
#define HW  (HH * WWD)         // per-channel advance in floats
#define CHW (CC * HH * WWD)

__global__ __launch_bounds__(512, 4) void lc2d_kernel(
    const float* __restrict__ x, const float* __restrict__ wgt,
    const float* __restrict__ bias, float* __restrict__ out)
{
    // per chunk: X tile 2kh x 32b x 32w = 2048 floats; W half-tile 2kh x 32f x 32w = 2048
    __shared__ __align__(16) float Xs[4][2048];   // 32 KB
    __shared__ __align__(16) float Ws[4][2048];   // 32 KB  (64 KB total -> 2 blocks/CU)

    const int tid  = threadIdx.x;
    const int id   = blockIdx.x;           // [0,512)
    const int fblk = id >> 8;              // which 32-f half
    const int low  = id & 255;
    // ids differing by 128 share 128-B output lines and the same XCD (128%8==0).
    const int oct = ((low & 1) << 1) | (low >> 7);   // 0..3 -> oc0 = oct*16
    const int orr = (low >> 1) & 63;
    const int w0  = oct * 32;                         // 32 w-floats, 128-B aligned
    const int h0  = orr * 2;

    const int lane = tid & 63;
    const int wv   = tid >> 6;        // wave 0..7
    const int chk  = lane & 7;        // 16-B chunk within a 128-B row
    const int sub  = lane >> 3;       // row within this wave's 8-row slot

    // ---- staging pointers (chunk c=0). LDS row r = s*32 + (b or fl), r in [0,64).
    // wave wv stages rows [wv*8, wv*8+8): one gload_lds for X, one for W, per chunk.
    const int r  = wv * 8 + sub;
    const int sr = r >> 5;            // kh
    const int br = r & 31;            // b (for X) / fl (for W)
    const float* gx = x   + (((br * CC) * HH) + h0 + sr) * WWD + w0 + chk * 4;
    const float* gw = wgt + ((((fblk * 32 + br) * CC) * HH) + h0 + sr) * WWD + w0 + chk * 4;

    auto issue = [&](int p) {
        __builtin_amdgcn_global_load_lds(
            (const __attribute__((address_space(1))) void*)gx,
            (__attribute__((address_space(3))) void*)(&Xs[p][wv * 256]), 16, 0, 0);
        __builtin_amdgcn_global_load_lds(
            (const __attribute__((address_space(1))) void*)gw,
            (__attribute__((address_space(3))) void*)(&Ws[p][wv * 256]), 16, 0, 0);
        gx += HW; gw += HW;           // next channel
    };

    // ---- compute mapping: ocg = w 4-float chunk (2 oc), bg -> 4 b, wv -> 4 f
    const int ocg = tid & 7;
    const int bg  = (tid >> 3) & 7;
    const int xoff = bg * 128 + ocg * 4;   // row bg*4, col ocg*4
    const int woff = wv * 128 + ocg * 4;   // row wv*4, col ocg*4

    float acc0[4][4], acc1[4][4];          // [i=b][q=f], oc even / oc odd
#pragma unroll
    for (int i = 0; i < 4; ++i)
#pragma unroll
        for (int q = 0; q < 4; ++q) { acc0[i][q] = 0.f; acc1[i][q] = 0.f; }

    // prologue: 4 chunks in flight (8 loads/wave outstanding)
    issue(0); issue(1); issue(2); issue(3);

    for (int it = 0; it < NIT; ++it) {
        // wait for chunk `it`: loads newer than it = 2 * min(3, NIT-1-it)
        const int rem = NIT - 1 - it;
        if (rem >= 3)      asm volatile("s_waitcnt vmcnt(6)");
        else if (rem == 2) asm volatile("s_waitcnt vmcnt(4)");
        else if (rem == 1) asm volatile("s_waitcnt vmcnt(2)");
        else               asm volatile("s_waitcnt vmcnt(0)");
        __builtin_amdgcn_sched_barrier(0);
        __builtin_amdgcn_s_barrier();          // raw barrier: NO vmcnt(0) drain
        __builtin_amdgcn_sched_barrier(0);

        const int p = it & 3;
        const float* Xp = Xs[p];
        const float* Wp = Ws[p];
#pragma unroll
        for (int s = 0; s < 2; ++s) {          // kh
            const float4* xr = (const float4*)(Xp + s * 1024 + xoff);
            const float4* wr = (const float4*)(Wp + s * 1024 + woff);
            float4 xa[4], wb[4];
#pragma unroll
            for (int i = 0; i < 4; ++i) xa[i] = xr[i * 8];   // b = bg*4 + i
#pragma unroll
            for (int q = 0; q < 4; ++q) wb[q] = wr[q * 8];   // f = fblk*32 + wv*4 + q
#pragma unroll
            for (int i = 0; i < 4; ++i)
#pragma unroll
                for (int q = 0; q < 4; ++q) {
                    acc0[i][q] = fmaf(xa[i].x, wb[q].x, acc0[i][q]);
                    acc0[i][q] = fmaf(xa[i].y, wb[q].y, acc0[i][q]);
                    acc1[i][q] = fmaf(xa[i].z, wb[q].z, acc1[i][q]);
                    acc1[i][q] = fmaf(xa[i].w, wb[q].w, acc1[i][q]);
                }
        }
        __builtin_amdgcn_sched_barrier(0);
        __builtin_amdgcn_s_barrier();          // all waves done reading buf p
        __builtin_amdgcn_sched_barrier(0);
        if (it + 4 < NIT) issue(p);            // refill freed buffer; stays in flight
    }

    // ---- epilogue: bias (raw reshape [F][OR][OC]) + relu, float2 per (b,f)
    const int oc0 = oct * 16 + ocg * 2;
#pragma unroll
    for (int q = 0; q < 4; ++q) {
        const int f = fblk * 32 + wv * 4 + q;
        const float2 bv = *(const float2*)(bias + f * (ORR * OCC) + orr * OCC + oc0);
#pragma unroll
        for (int i = 0; i < 4; ++i) {
            const int b = bg * 4 + i;
            float2 o;
            o.x = fmaxf(acc0[i][q] + bv.x, 0.f);
            o.y = fmaxf(acc1[i][q] + bv.y, 0.f);
            *(float2*)(out + (((b * FF + f) * ORR + orr) * OCC) + oc0) = o;
        }
    }
}

extern "C" void kernel_launch(void* const* d_in, const int* in_sizes, int n_in,
                              void* d_out, int out_size, void* d_ws, size_t ws_size,
                              hipStream_t stream) {
    (void)in_sizes; (void)n_in; (void)d_ws; (void)ws_size; (void)out_size;
    const float* x    = (const float*)d_in[0];
    const float* wgt  = (const float*)d_in[1];
    const float* bias = (const float*)d_in[2];
    float* out        = (float*)d_out;
    lc2d_kernel<<<dim3(512, 1, 1), dim3(512, 1, 1), 0, stream>>>(x, wgt, bias, out);
}